// Round 1
// baseline (463.098 us; speedup 1.0000x reference)
//
#include <hip/hip_runtime.h>

// EventMessagePassingEdge: per-edge 2-layer MLP with gathered node features.
//   evt[e] = [h[src[e]], e_h[e], h[dst[e]]]           (192 fp32)
//   x      = evt @ W1 + b1                            (64)
//   out    = relu([x, ext[e]] @ W2 + b2)              (64 fp32)
// V2 strategy (occupancy fix — kernel was latency-bound at 2 waves/SIMD):
//   - A-fragments for layer 1 are gathered DIRECTLY global->register:
//     lane l needs evt[l&15][kc*32+(l>>4)*8 + j], 8 contiguous floats ->
//     two dwordx4 loads per kc. No per-wave evt LDS staging at all.
//   - LDS = W1/W2 frags (36 KB) + per-wave 3 KB x2 round-trip buffer only.
//     512-thread blocks, 60 KB LDS -> 2 blocks/CU = 16 waves/CU = 4 w/SIMD
//     (double the old occupancy). __launch_bounds__(512,4) caps VGPR at 128.
//   - src/dst indices for iteration it+1 prefetched during iteration it.
// W1/W2 staged once per block in LDS in B-fragment order (conflict-free b128).
// No __syncthreads in main loop.

typedef __attribute__((ext_vector_type(8))) short bf16x8;
typedef __attribute__((ext_vector_type(4))) float f32x4;
typedef __attribute__((ext_vector_type(4))) short s16x4;

__device__ __forceinline__ short f2bf(float f) {
  // round-to-nearest-even fp32 -> bf16
  unsigned u = __builtin_bit_cast(unsigned, f);
  u = (u + 0x7FFFu + ((u >> 16) & 1u)) >> 16;
  return (short)u;
}

#define ITERS 4  // 8 waves * 16 edges * 4 iters = 512 edges/block

// LDS layout (shorts):
//   [0,     12288)  W1 frags: slot s = (kc*4+nt)*64 + lane, 8 bf16 each
//   [12288, 18432)  W2 frags: slot s = (kc*4+nt)*64 + lane, 8 bf16 each
//   [18432, 30720)  per-wave x2 region, 1536 shorts (3072 B) per wave (8 waves)
//     x2 slot = kc*64 + quad*16 + m (kc 0..2) holds x2[m][kc*32+quad*8+j]
// total 61440 B -> 2 blocks/CU.

__global__ __launch_bounds__(512, 4) void edge_mp_kernel(
    const float* __restrict__ h, const float* __restrict__ e_h,
    const float* __restrict__ ext, const float* __restrict__ W1,
    const float* __restrict__ b1, const float* __restrict__ W2,
    const float* __restrict__ b2, const int* __restrict__ src,
    const int* __restrict__ dst, float* __restrict__ out, int E) {
  __shared__ __align__(16) short lds[30720];
  const int tid = threadIdx.x;
  const int l = tid & 63;   // lane
  const int wid = tid >> 6; // wave in block (0..7)
  const int i = l & 15;     // MFMA idx (col of C, row of A) = edge within tile
  const int q = l >> 4;     // MFMA quad
  const int i2 = l >> 2;    // ext staging: edge within tile
  const int c = l & 3;      // ext staging: chunk lane

  // ---- stage W1 fragments (1536 slots) ----
  for (int s = tid; s < 1536; s += 512) {
    int kc = s >> 8, nt = (s >> 6) & 3, ll = s & 63;
    int k0 = kc * 32 + ((ll >> 4) * 8), n = nt * 16 + (ll & 15);
#pragma unroll
    for (int j = 0; j < 8; ++j) lds[s * 8 + j] = f2bf(W1[(k0 + j) * 64 + n]);
  }
  // ---- stage W2 fragments (768 slots) ----
  for (int s = tid; s < 768; s += 512) {
    int kc = s >> 8, nt = (s >> 6) & 3, ll = s & 63;
    int k0 = kc * 32 + ((ll >> 4) * 8), n = nt * 16 + (ll & 15);
#pragma unroll
    for (int j = 0; j < 8; ++j)
      lds[12288 + s * 8 + j] = f2bf(W2[(k0 + j) * 64 + n]);
  }
  __syncthreads();

  float b1v[4], b2v[4];
#pragma unroll
  for (int nt = 0; nt < 4; ++nt) {
    b1v[nt] = b1[nt * 16 + i];
    b2v[nt] = b2[nt * 16 + i];
  }

  short* xw = &lds[18432 + wid * 1536];

  const int base = blockIdx.x * (128 * ITERS) + wid * 16;

  // prefetch first iteration's indices
  int nS = 0, nD = 0;
  if (base < E) {
    int e = base + i;
    if (e >= E) e = E - 1;
    nS = src[e];
    nD = dst[e];
  }

#pragma unroll 1
  for (int it = 0; it < ITERS; ++it) {
    const int e0 = base + it * 128;
    if (e0 >= E) break;
    int e = e0 + i;
    if (e >= E) e = E - 1;

    // ---- issue all layer-1 A-fragment gathers (direct to registers) ----
    // lane (i,q): 8 contiguous floats at k_local = t*32 + q*8 per source.
    const float* ps = h + (size_t)nS * 64 + q * 8;
    const float* pe = e_h + (size_t)e * 64 + q * 8;
    const float* pd = h + (size_t)nD * 64 + q * 8;
    f32x4 L[12];
    L[0] = *(const f32x4*)(ps);
    L[1] = *(const f32x4*)(ps + 4);
    L[2] = *(const f32x4*)(ps + 32);
    L[3] = *(const f32x4*)(ps + 36);
    L[4] = *(const f32x4*)(pe);
    L[5] = *(const f32x4*)(pe + 4);
    L[6] = *(const f32x4*)(pe + 32);
    L[7] = *(const f32x4*)(pe + 36);
    L[8] = *(const f32x4*)(pd);
    L[9] = *(const f32x4*)(pd + 4);
    L[10] = *(const f32x4*)(pd + 32);
    L[11] = *(const f32x4*)(pd + 36);

    // ---- ext loads (coalesced, i2/c pattern) ----
    int ex = e0 + i2;
    if (ex >= E) ex = E - 1;
    f32x4 X0 = *(const f32x4*)(ext + (size_t)ex * 32 + 4 * c);
    f32x4 X1 = *(const f32x4*)(ext + (size_t)ex * 32 + 16 + 4 * c);

    // ---- prefetch next iteration's indices (off the critical chain) ----
    if (it + 1 < ITERS) {
      const int en0 = e0 + 128;
      if (en0 < E) {
        int en = en0 + i;
        if (en >= E) en = E - 1;
        nS = src[en];
        nD = dst[en];
      }
    }

    // ---- layer 1: 6 kc x 4 ntile MFMAs, A from registers ----
    f32x4 acc[4] = {{0.f, 0.f, 0.f, 0.f},
                    {0.f, 0.f, 0.f, 0.f},
                    {0.f, 0.f, 0.f, 0.f},
                    {0.f, 0.f, 0.f, 0.f}};
#pragma unroll
    for (int kc = 0; kc < 6; ++kc) {
      bf16x8 a;
#pragma unroll
      for (int j = 0; j < 4; ++j) {
        a[j] = f2bf(L[2 * kc][j]);
        a[4 + j] = f2bf(L[2 * kc + 1][j]);
      }
#pragma unroll
      for (int nt = 0; nt < 4; ++nt) {
        bf16x8 b = *(const bf16x8*)&lds[((kc * 4 + nt) * 64 + l) * 8];
        acc[nt] = __builtin_amdgcn_mfma_f32_16x16x32_bf16(a, b, acc[nt], 0, 0, 0);
      }
    }

    // ---- x (C-layout) + b1 -> bf16 -> x2 A-layout in LDS ----
#pragma unroll
    for (int nt = 0; nt < 4; ++nt) {
      const int n = nt * 16 + i;
      const int kc2 = n >> 5, qA = (n & 31) >> 3, j = n & 7;
#pragma unroll
      for (int r = 0; r < 4; ++r) {
        const int m = q * 4 + r;  // C row = edge within tile
        xw[(kc2 * 64 + qA * 16 + m) * 8 + j] = f2bf(acc[nt][r] + b1v[nt]);
      }
    }
    // ---- ext -> x2 chunk kc2 = 2 ----
#pragma unroll
    for (int t = 0; t < 2; ++t) {
      f32x4 v = t ? X1 : X0;
      const int quad = 2 * t + (c >> 1);
      const int j0 = 4 * (c & 1);
      s16x4 p;
      p[0] = f2bf(v[0]);
      p[1] = f2bf(v[1]);
      p[2] = f2bf(v[2]);
      p[3] = f2bf(v[3]);
      *(s16x4*)&xw[(2 * 64 + quad * 16 + i2) * 8 + j0] = p;
    }

    // ---- layer 2: 3 kc x 4 ntile MFMAs ----
    f32x4 acc2[4] = {{0.f, 0.f, 0.f, 0.f},
                     {0.f, 0.f, 0.f, 0.f},
                     {0.f, 0.f, 0.f, 0.f},
                     {0.f, 0.f, 0.f, 0.f}};
#pragma unroll
    for (int kc = 0; kc < 3; ++kc) {
      bf16x8 a = *(const bf16x8*)&xw[(kc * 64 + l) * 8];
#pragma unroll
      for (int nt = 0; nt < 4; ++nt) {
        bf16x8 b = *(const bf16x8*)&lds[12288 + ((kc * 4 + nt) * 64 + l) * 8];
        acc2[nt] =
            __builtin_amdgcn_mfma_f32_16x16x32_bf16(a, b, acc2[nt], 0, 0, 0);
      }
    }

    // ---- epilogue: +b2, relu, store fp32 (C-layout) ----
#pragma unroll
    for (int nt = 0; nt < 4; ++nt) {
      const int n = nt * 16 + i;
#pragma unroll
      for (int r = 0; r < 4; ++r) {
        const int er = e0 + q * 4 + r;
        if (er < E) {
          float v = acc2[nt][r] + b2v[nt];
          out[(size_t)er * 64 + n] = fmaxf(v, 0.f);
        }
      }
    }
  }
}

extern "C" void kernel_launch(void* const* d_in, const int* in_sizes, int n_in,
                              void* d_out, int out_size, void* d_ws,
                              size_t ws_size, hipStream_t stream) {
  const float* h = (const float*)d_in[0];
  const float* e_h = (const float*)d_in[1];
  const float* ext = (const float*)d_in[2];
  const float* W1 = (const float*)d_in[3];
  const float* b1 = (const float*)d_in[4];
  const float* W2 = (const float*)d_in[5];
  const float* b2 = (const float*)d_in[6];
  const int* src = (const int*)d_in[7];
  const int* dst = (const int*)d_in[8];
  float* out = (float*)d_out;
  const int E = in_sizes[7];  // 800000
  const int blocks = (E + (128 * ITERS) - 1) / (128 * ITERS);
  hipLaunchKernelGGL(edge_mp_kernel, dim3(blocks), dim3(512), 0, stream, h, e_h,
                     ext, W1, b1, W2, b2, src, dst, out, E);
}